// Round 2
// baseline (417.241 us; speedup 1.0000x reference)
//
#include <hip/hip_runtime.h>
#include <hip/hip_bf16.h>

typedef __bf16 bf16_t;
typedef __bf16 bf16x8 __attribute__((ext_vector_type(8)));
typedef __bf16 bf16x4 __attribute__((ext_vector_type(4)));
typedef float f32x4 __attribute__((ext_vector_type(4)));

#define QS   256.0f
#define QINV 0.00390625f

__device__ __forceinline__ void async_copy16(const bf16_t* g, bf16_t* l) {
  __builtin_amdgcn_global_load_lds(
      (__attribute__((address_space(1))) void*)g,
      (__attribute__((address_space(3))) void*)l,
      16, 0, 0);
}

// Stage one 16KB unit (128 rows x 64 cols bf16) of a 256x64 tile into LDS.
// SHIFT=6 (A units: 64-row segments), SHIFT=5 (B units: 32-row segments).
// halfOff selects which interleaved half (A: 0/64, B: 0/32).
// Global chunk pre-permuted so linear LDS dest ends up XOR-swizzled:
// phys chunk c of row r holds logical chunk c ^ (r & 7).
template <int SHIFT>
__device__ __forceinline__ void stage_unit(const bf16_t* __restrict__ gk, bf16_t* lbuf,
                                           int K, int halfOff, int tid) {
  const int scb = (((tid & 7) ^ ((tid >> 3) & 7)) << 3);  // swizzled global chunk (elems)
  const int MASK = (1 << SHIFT) - 1;
#pragma unroll
  for (int q = 0; q < 2; ++q) {
    const int u  = q * 64 + (tid >> 3);          // per-lane unit-row
    const int u0 = q * 64 + ((tid >> 6) << 3);   // wave-uniform base unit-row
    const int row  = halfOff + (u  & MASK) + ((u  >> SHIFT) << (SHIFT + 1));
    const int row0 = halfOff + (u0 & MASK) + ((u0 >> SHIFT) << (SHIFT + 1));
    async_copy16(gk + (size_t)row * K + scb, lbuf + row0 * 64);
  }
}

// read-side swizzle: physical chunk = logical ^ (row & 7)
__device__ __forceinline__ bf16x8 ldfrag(const bf16_t* buf, int row, int ks, int lq) {
  const int phys = ((ks << 2) | lq) ^ (row & 7);
  return *(const bf16x8*)(buf + row * 64 + (phys << 3));
}

// C = quantize-epilogue(A @ Bt^T + bias)
// 256x256 tile, BK=64, 8 waves (2Mx4N), per-wave 128x64 via acc[8][4].
// 8-phase-per-2-K-tiles schedule (4 phases/K-tile), counted vmcnt (never 0
// in steady state), raw s_barrier, setprio around MFMA clusters.
// LDS: 2 dbuf x (A 32KB + B 32KB) = 128 KiB. GELU PWL table in registers.
template <bool GELU, typename OutT, bool XSWZ>
__global__ __launch_bounds__(512, 2)
void gemm_tile(const bf16_t* __restrict__ A, const bf16_t* __restrict__ Bt,
               const float* __restrict__ bias, OutT* __restrict__ C,
               int M, int N, int K) {
  __shared__ __attribute__((aligned(16))) bf16_t As[2 * 256 * 64];
  __shared__ __attribute__((aligned(16))) bf16_t Bs[2 * 256 * 64];

  const int tid = threadIdx.x;
  const int lane = tid & 63;
  const int wid = tid >> 6;   // 0..7
  const int wr = wid >> 2;    // wave row (0/1) -> 128 rows
  const int wc = wid & 3;     // wave col (0..3) -> 64 cols
  const int l15 = lane & 15;
  const int lq = lane >> 4;   // 0..3

  // register-resident PWL table: lane l holds y(x_l) and slope to x_{l+1}
  float ytA = 0.f, ytS = 0.f;
  if (GELU) {
    float xv = -4.0f + 0.25f * (float)lane;
    float y0 = 0.5f * xv * (1.0f + erff(xv * 0.70710678f));
    float xv1 = xv + 0.25f;
    float y1 = 0.5f * xv1 * (1.0f + erff(xv1 * 0.70710678f));
    ytA = y0;
    ytS = y1 - y0;
  }

  int bx = blockIdx.x, by = blockIdx.y;
  if (XSWZ) {
    // bijective chunked XCD swizzle: XCD k (= flat&7 round-robin) gets a
    // contiguous chunk of row-major block ids -> same-M-row blocks share L2.
    const int gx = gridDim.x;
    const int nwg = gx * gridDim.y;       // divisible by 8 here
    const int f = by * gx + bx;
    const int chunk = nwg >> 3;
    const int f2 = (f & 7) * chunk + (f >> 3);
    bx = f2 % gx;
    by = f2 / gx;
  }

  const int mBase = by * 256;
  const int nBase = bx * 256;
  const bf16_t* aTile = A + (size_t)mBase * K;
  const bf16_t* bTile = Bt + (size_t)nBase * K;

  f32x4 acc[8][4];
#pragma unroll
  for (int i = 0; i < 8; ++i)
#pragma unroll
    for (int j = 0; j < 4; ++j)
      acc[i][j] = (f32x4){0.f, 0.f, 0.f, 0.f};

  bf16x8 fa[2][4];      // A frags [ks][i], current i-half
  bf16x8 fb[2][2][2];   // B frags [jh][ks][j], both j-halves live

  const int nT = K >> 6;
  const int rA0 = wr * 128 + l15;
  const int rB0 = wc * 64 + l15;

  // ---- prologue: stage all 4 units of K-tile 0 (order = first-use order)
  stage_unit<6>(aTile, As, K, 0, tid);    // U0: A i-half0
  stage_unit<5>(bTile, Bs, K, 0, tid);    // U1: B j-half0
  stage_unit<5>(bTile, Bs, K, 32, tid);   // U2: B j-half1
  stage_unit<6>(aTile, As, K, 64, tid);   // U3: A i-half1
  asm volatile("s_waitcnt vmcnt(4)" ::: "memory");  // U0,U1 resident; U2,U3 in flight
  __builtin_amdgcn_s_barrier();

  for (int t = 0; t < nT; ++t) {
    const bf16_t* Ab = As + (t & 1) * 16384;
    const bf16_t* Bb = Bs + (t & 1) * 16384;
    bf16_t* An = As + ((t & 1) ^ 1) * 16384;
    bf16_t* Bn = Bs + ((t & 1) ^ 1) * 16384;
    const bf16_t* aN = aTile + (size_t)(t + 1) * 64;
    const bf16_t* bN = bTile + (size_t)(t + 1) * 64;
    const bool nl = (t + 1 < nT);

    // -------- P0: quadrant (ihalf0 x jhalf0); reads U0+U1; stages next U0
#pragma unroll
    for (int ks = 0; ks < 2; ++ks) {
#pragma unroll
      for (int i = 0; i < 4; ++i) fa[ks][i] = ldfrag(Ab, rA0 + i * 16, ks, lq);
#pragma unroll
      for (int j = 0; j < 2; ++j) fb[0][ks][j] = ldfrag(Bb, rB0 + j * 16, ks, lq);
    }
    if (nl) {
      stage_unit<6>(aN, An, K, 0, tid);
      asm volatile("s_waitcnt vmcnt(4)" ::: "memory");  // drains this tile's U2
    } else {
      asm volatile("s_waitcnt vmcnt(2)" ::: "memory");
    }
    __builtin_amdgcn_s_barrier();
    asm volatile("s_waitcnt lgkmcnt(0)" ::: "memory");
    __builtin_amdgcn_sched_barrier(0);
    __builtin_amdgcn_s_setprio(1);
#pragma unroll
    for (int ks = 0; ks < 2; ++ks)
#pragma unroll
      for (int i = 0; i < 4; ++i)
#pragma unroll
        for (int j = 0; j < 2; ++j)
          acc[i][j] = __builtin_amdgcn_mfma_f32_16x16x32_bf16(fa[ks][i], fb[0][ks][j], acc[i][j], 0, 0, 0);
    __builtin_amdgcn_s_setprio(0);
    __builtin_amdgcn_s_barrier();

    // -------- P1: quadrant (ihalf0 x jhalf1); reads U2; stages next U1
#pragma unroll
    for (int ks = 0; ks < 2; ++ks)
#pragma unroll
      for (int j = 0; j < 2; ++j) fb[1][ks][j] = ldfrag(Bb, rB0 + 32 + j * 16, ks, lq);
    if (nl) {
      stage_unit<5>(bN, Bn, K, 0, tid);
      asm volatile("s_waitcnt vmcnt(4)" ::: "memory");  // drains this tile's U3
    } else {
      asm volatile("s_waitcnt vmcnt(0)" ::: "memory");
    }
    __builtin_amdgcn_s_barrier();
    asm volatile("s_waitcnt lgkmcnt(0)" ::: "memory");
    __builtin_amdgcn_sched_barrier(0);
    __builtin_amdgcn_s_setprio(1);
#pragma unroll
    for (int ks = 0; ks < 2; ++ks)
#pragma unroll
      for (int i = 0; i < 4; ++i)
#pragma unroll
        for (int j = 0; j < 2; ++j)
          acc[i][2 + j] = __builtin_amdgcn_mfma_f32_16x16x32_bf16(fa[ks][i], fb[1][ks][j], acc[i][2 + j], 0, 0, 0);
    __builtin_amdgcn_s_setprio(0);
    __builtin_amdgcn_s_barrier();

    // -------- P2: quadrant (ihalf1 x jhalf1); reads U3; stages next U2
#pragma unroll
    for (int ks = 0; ks < 2; ++ks)
#pragma unroll
      for (int i = 0; i < 4; ++i) fa[ks][i] = ldfrag(Ab, rA0 + 64 + i * 16, ks, lq);
    if (nl) stage_unit<5>(bN, Bn, K, 32, tid);
    __builtin_amdgcn_s_barrier();
    asm volatile("s_waitcnt lgkmcnt(0)" ::: "memory");
    __builtin_amdgcn_sched_barrier(0);
    __builtin_amdgcn_s_setprio(1);
#pragma unroll
    for (int ks = 0; ks < 2; ++ks)
#pragma unroll
      for (int i = 0; i < 4; ++i)
#pragma unroll
        for (int j = 0; j < 2; ++j)
          acc[4 + i][2 + j] = __builtin_amdgcn_mfma_f32_16x16x32_bf16(fa[ks][i], fb[1][ks][j], acc[4 + i][2 + j], 0, 0, 0);
    __builtin_amdgcn_s_setprio(0);
    __builtin_amdgcn_s_barrier();

    // -------- P3: quadrant (ihalf1 x jhalf0); no new reads; stages next U3
    if (nl) {
      stage_unit<6>(aN, An, K, 64, tid);
      asm volatile("s_waitcnt vmcnt(4)" ::: "memory");  // drains next tile's U0,U1
    }
    __builtin_amdgcn_s_barrier();
    __builtin_amdgcn_sched_barrier(0);
    __builtin_amdgcn_s_setprio(1);
#pragma unroll
    for (int ks = 0; ks < 2; ++ks)
#pragma unroll
      for (int i = 0; i < 4; ++i)
#pragma unroll
        for (int j = 0; j < 2; ++j)
          acc[4 + i][j] = __builtin_amdgcn_mfma_f32_16x16x32_bf16(fa[ks][i], fb[0][ks][j], acc[4 + i][j], 0, 0, 0);
    __builtin_amdgcn_s_setprio(0);
    __builtin_amdgcn_s_barrier();
  }

  // ---- epilogue: bias + quantize (+ PWL GELU via register-table shuffle)
  float bj[4];
#pragma unroll
  for (int j = 0; j < 4; ++j)
    bj[j] = bias[nBase + wc * 64 + j * 16 + l15];

#pragma unroll
  for (int i = 0; i < 8; ++i) {
    const int rb = mBase + wr * 128 + i * 16 + lq * 4;
#pragma unroll
    for (int j = 0; j < 4; ++j) {
      const int cn = nBase + wc * 64 + j * 16 + l15;
#pragma unroll
      for (int r = 0; r < 4; ++r) {
        float c = acc[i][j][r] + bj[j];
        float v;
        if (GELU) {
          float xq = rintf(c * QS) * QINV;           // float2fix (Positional_0)
          float t = (xq + 4.0f) * 4.0f;              // exact: /0.25
          int ii = (int)t;
          ii = ii < 0 ? 0 : (ii > 31 ? 31 : ii);
          float f = t - (float)ii;
          float y0 = __shfl(ytA, ii);
          float sl = __shfl(ytS, ii);
          v = fmaf(f, sl, y0);
          v = (xq > 4.0f) ? xq : v;
          v = (xq < -4.0f) ? 0.0f : v;
          v = rintf(v * QS) * QINV;                  // quantize out (+Positional_1 idempotent)
        } else {
          v = rintf(c * QS) * QINV;                  // Positional_2
        }
        C[(size_t)(rb + r) * N + cn] = (OutT)v;
      }
    }
  }
}

__global__ void cvt_bf16_kernel(const float* __restrict__ in, bf16_t* __restrict__ out, int n4) {
  int idx = blockIdx.x * blockDim.x + threadIdx.x;
  if (idx < n4) {
    const float4 v = ((const float4*)in)[idx];
    bf16x4 o;
    o[0] = (bf16_t)v.x; o[1] = (bf16_t)v.y; o[2] = (bf16_t)v.z; o[3] = (bf16_t)v.w;
    ((bf16x4*)out)[idx] = o;
  }
}

// in: [R][C] f32 row-major -> out: [C][R] bf16 row-major
__global__ void transpose_cvt_kernel(const float* __restrict__ in, bf16_t* __restrict__ out,
                                     int R, int C) {
  __shared__ float t[32][33];
  const int c0 = blockIdx.x * 32;
  const int r0 = blockIdx.y * 32;
  const int tx = threadIdx.x;
  const int ty = threadIdx.y;  // 0..7
#pragma unroll
  for (int dy = 0; dy < 32; dy += 8)
    t[ty + dy][tx] = in[(size_t)(r0 + ty + dy) * C + c0 + tx];
  __syncthreads();
#pragma unroll
  for (int dy = 0; dy < 32; dy += 8)
    out[(size_t)(c0 + ty + dy) * R + r0 + tx] = (bf16_t)t[tx][ty + dy];
}

extern "C" void kernel_launch(void* const* d_in, const int* in_sizes, int n_in,
                              void* d_out, int out_size, void* d_ws, size_t ws_size,
                              hipStream_t stream) {
  const float* x  = (const float*)d_in[0];   // [32,512,1024] = [16384][1024]
  const float* w1 = (const float*)d_in[1];   // [1024][4096]
  const float* b1 = (const float*)d_in[2];   // [4096]
  const float* w2 = (const float*)d_in[3];   // [4096][1024]
  const float* b2 = (const float*)d_in[4];   // [1024]
  float* out = (float*)d_out;                // [16384][1024]

  const int M = 16384, D = 1024, F = 4096;

  char* ws = (char*)d_ws;
  size_t off = 0;
  bf16_t* xb  = (bf16_t*)(ws + off); off += (size_t)M * D * 2;  // 33.5 MB
  bf16_t* w1t = (bf16_t*)(ws + off); off += (size_t)D * F * 2;  //  8.4 MB
  bf16_t* w2t = (bf16_t*)(ws + off); off += (size_t)F * D * 2;  //  8.4 MB
  bf16_t* h   = (bf16_t*)(ws + off);                            // 134.2 MB

  cvt_bf16_kernel<<<(M * D / 4 + 255) / 256, 256, 0, stream>>>(x, xb, M * D / 4);
  transpose_cvt_kernel<<<dim3(F / 32, D / 32), dim3(32, 8), 0, stream>>>(w1, w1t, D, F);
  transpose_cvt_kernel<<<dim3(D / 32, F / 32), dim3(32, 8), 0, stream>>>(w2, w2t, F, D);

  // GEMM1 + quantize + PWL-GELU + quantize -> h (bf16)
  gemm_tile<true, bf16_t, false><<<dim3(F / 256, M / 256), 512, 0, stream>>>(xb, w1t, b1, h, M, F, D);
  // GEMM2 + quantize -> out (f32); h (134MB) re-read 4x -> XCD-chunked swizzle
  gemm_tile<false, float, true><<<dim3(D / 256, M / 256), 512, 0, stream>>>(h, w2t, b2, out, M, D, F);
}

// Round 3
// 417.142 us; speedup vs baseline: 1.0002x; 1.0002x over previous
//
#include <hip/hip_runtime.h>
#include <hip/hip_bf16.h>

typedef __bf16 bf16_t;
typedef __bf16 bf16x8 __attribute__((ext_vector_type(8)));
typedef __bf16 bf16x4 __attribute__((ext_vector_type(4)));
typedef float f32x4 __attribute__((ext_vector_type(4)));

#define QS   256.0f
#define QINV 0.00390625f

__device__ __forceinline__ void async_copy16(const bf16_t* g, bf16_t* l) {
  __builtin_amdgcn_global_load_lds(
      (__attribute__((address_space(1))) void*)g,
      (__attribute__((address_space(3))) void*)l,
      16, 0, 0);
}

// Stage one 16KB unit (128 rows x 64 cols bf16) of a 256x64 tile into LDS.
// SHIFT=6 (A units: 64-row segments), SHIFT=5 (B units: 32-row segments).
// halfOff selects which interleaved half (A: 0/64, B: 0/32).
// Global chunk pre-permuted so linear LDS dest ends up XOR-swizzled:
// phys chunk c of row r holds logical chunk c ^ (r & 7).
template <int SHIFT>
__device__ __forceinline__ void stage_unit(const bf16_t* __restrict__ gk, bf16_t* lbuf,
                                           int K, int halfOff, int tid) {
  const int scb = (((tid & 7) ^ ((tid >> 3) & 7)) << 3);  // swizzled global chunk (elems)
  const int MASK = (1 << SHIFT) - 1;
#pragma unroll
  for (int q = 0; q < 2; ++q) {
    const int u  = q * 64 + (tid >> 3);          // per-lane unit-row
    const int u0 = q * 64 + ((tid >> 6) << 3);   // wave-uniform base unit-row
    const int row  = halfOff + (u  & MASK) + ((u  >> SHIFT) << (SHIFT + 1));
    const int row0 = halfOff + (u0 & MASK) + ((u0 >> SHIFT) << (SHIFT + 1));
    async_copy16(gk + (size_t)row * K + scb, lbuf + row0 * 64);
  }
}

// read-side swizzle: physical chunk = logical ^ (row & 7)
__device__ __forceinline__ bf16x8 ldfrag(const bf16_t* buf, int row, int ks, int lq) {
  const int phys = ((ks << 2) | lq) ^ (row & 7);
  return *(const bf16x8*)(buf + row * 64 + (phys << 3));
}

// One K-tile (BK=64): 4 phases, each {ds_read frags | stage next unit |
// counted vmcnt | barrier | lgkmcnt(0)+sched_barrier | setprio+16 MFMA | barrier}.
// Ab/Bb: read buffers (this tile). An/Bn: write buffers (next tile, DMA dest).
// Distinct __shared__ objects + __restrict__ -> SIInsertWaitcnts' LDS-DMA
// tracking never forces a drain before reads of Ab/Bb while An/Bn DMAs fly.
__device__ __forceinline__ void ktile(
    const bf16_t* __restrict__ Ab, const bf16_t* __restrict__ Bb,
    bf16_t* __restrict__ An, bf16_t* __restrict__ Bn,
    const bf16_t* __restrict__ aN, const bf16_t* __restrict__ bN,
    const bool nl, const int tid, const int rA0, const int rB0, const int lq,
    const int K, f32x4 (&acc)[8][4]) {
  bf16x8 fa[2][4];      // A frags [ks][i], current i-half
  bf16x8 fb[2][2][2];   // B frags [jh][ks][j], both j-halves live

  // -------- P0: quadrant (ihalf0 x jhalf0); reads U0+U1; stages next U0
#pragma unroll
  for (int ks = 0; ks < 2; ++ks) {
#pragma unroll
    for (int i = 0; i < 4; ++i) fa[ks][i] = ldfrag(Ab, rA0 + i * 16, ks, lq);
#pragma unroll
    for (int j = 0; j < 2; ++j) fb[0][ks][j] = ldfrag(Bb, rB0 + j * 16, ks, lq);
  }
  if (nl) {
    stage_unit<6>(aN, An, K, 0, tid);
    asm volatile("s_waitcnt vmcnt(4)" ::: "memory");  // drains this tile's U2
  } else {
    asm volatile("s_waitcnt vmcnt(2)" ::: "memory");
  }
  __builtin_amdgcn_s_barrier();
  asm volatile("s_waitcnt lgkmcnt(0)" ::: "memory");
  __builtin_amdgcn_sched_barrier(0);
  __builtin_amdgcn_s_setprio(1);
#pragma unroll
  for (int ks = 0; ks < 2; ++ks)
#pragma unroll
    for (int i = 0; i < 4; ++i)
#pragma unroll
      for (int j = 0; j < 2; ++j)
        acc[i][j] = __builtin_amdgcn_mfma_f32_16x16x32_bf16(fa[ks][i], fb[0][ks][j], acc[i][j], 0, 0, 0);
  __builtin_amdgcn_s_setprio(0);
  __builtin_amdgcn_s_barrier();

  // -------- P1: quadrant (ihalf0 x jhalf1); reads U2; stages next U1
#pragma unroll
  for (int ks = 0; ks < 2; ++ks)
#pragma unroll
    for (int j = 0; j < 2; ++j) fb[1][ks][j] = ldfrag(Bb, rB0 + 32 + j * 16, ks, lq);
  if (nl) {
    stage_unit<5>(bN, Bn, K, 0, tid);
    asm volatile("s_waitcnt vmcnt(4)" ::: "memory");  // drains this tile's U3
  } else {
    asm volatile("s_waitcnt vmcnt(0)" ::: "memory");
  }
  __builtin_amdgcn_s_barrier();
  asm volatile("s_waitcnt lgkmcnt(0)" ::: "memory");
  __builtin_amdgcn_sched_barrier(0);
  __builtin_amdgcn_s_setprio(1);
#pragma unroll
  for (int ks = 0; ks < 2; ++ks)
#pragma unroll
    for (int i = 0; i < 4; ++i)
#pragma unroll
      for (int j = 0; j < 2; ++j)
        acc[i][2 + j] = __builtin_amdgcn_mfma_f32_16x16x32_bf16(fa[ks][i], fb[1][ks][j], acc[i][2 + j], 0, 0, 0);
  __builtin_amdgcn_s_setprio(0);
  __builtin_amdgcn_s_barrier();

  // -------- P2: quadrant (ihalf1 x jhalf1); reads U3; stages next U2
#pragma unroll
  for (int ks = 0; ks < 2; ++ks)
#pragma unroll
    for (int i = 0; i < 4; ++i) fa[ks][i] = ldfrag(Ab, rA0 + 64 + i * 16, ks, lq);
  if (nl) stage_unit<5>(bN, Bn, K, 32, tid);
  __builtin_amdgcn_s_barrier();
  asm volatile("s_waitcnt lgkmcnt(0)" ::: "memory");
  __builtin_amdgcn_sched_barrier(0);
  __builtin_amdgcn_s_setprio(1);
#pragma unroll
  for (int ks = 0; ks < 2; ++ks)
#pragma unroll
    for (int i = 0; i < 4; ++i)
#pragma unroll
      for (int j = 0; j < 2; ++j)
        acc[4 + i][2 + j] = __builtin_amdgcn_mfma_f32_16x16x32_bf16(fa[ks][i], fb[1][ks][j], acc[4 + i][2 + j], 0, 0, 0);
  __builtin_amdgcn_s_setprio(0);
  __builtin_amdgcn_s_barrier();

  // -------- P3: quadrant (ihalf1 x jhalf0); no new reads; stages next U3
  if (nl) {
    stage_unit<6>(aN, An, K, 64, tid);
    asm volatile("s_waitcnt vmcnt(4)" ::: "memory");  // drains next tile's U0,U1
  }
  __builtin_amdgcn_s_barrier();
  __builtin_amdgcn_sched_barrier(0);
  __builtin_amdgcn_s_setprio(1);
#pragma unroll
  for (int ks = 0; ks < 2; ++ks)
#pragma unroll
    for (int i = 0; i < 4; ++i)
#pragma unroll
      for (int j = 0; j < 2; ++j)
        acc[4 + i][j] = __builtin_amdgcn_mfma_f32_16x16x32_bf16(fa[ks][i], fb[0][ks][j], acc[4 + i][j], 0, 0, 0);
  __builtin_amdgcn_s_setprio(0);
  __builtin_amdgcn_s_barrier();
}

// C = quantize-epilogue(A @ Bt^T + bias)
// 256x256 tile, BK=64, 8 waves (2Mx4N), per-wave 128x64 via acc[8][4].
// K-loop unrolled by 2 with 4 DISTINCT __shared__ buffers so double-buffer
// selection is compile-time (precise LDS-DMA waitcnt tracking; counted
// vmcnt never drains the prefetch queue). Requires nT even.
template <bool GELU, typename OutT, bool XSWZ>
__global__ __launch_bounds__(512, 2)
void gemm_tile(const bf16_t* __restrict__ A, const bf16_t* __restrict__ Bt,
               const float* __restrict__ bias, OutT* __restrict__ C,
               int M, int N, int K) {
  __shared__ __attribute__((aligned(16))) bf16_t As0[256 * 64];
  __shared__ __attribute__((aligned(16))) bf16_t Bs0[256 * 64];
  __shared__ __attribute__((aligned(16))) bf16_t As1[256 * 64];
  __shared__ __attribute__((aligned(16))) bf16_t Bs1[256 * 64];

  const int tid = threadIdx.x;
  const int lane = tid & 63;
  const int wid = tid >> 6;   // 0..7
  const int wr = wid >> 2;    // wave row (0/1) -> 128 rows
  const int wc = wid & 3;     // wave col (0..3) -> 64 cols
  const int l15 = lane & 15;
  const int lq = lane >> 4;   // 0..3

  // register-resident PWL table: lane l holds y(x_l) and slope to x_{l+1}
  float ytA = 0.f, ytS = 0.f;
  if (GELU) {
    float xv = -4.0f + 0.25f * (float)lane;
    float y0 = 0.5f * xv * (1.0f + erff(xv * 0.70710678f));
    float xv1 = xv + 0.25f;
    float y1 = 0.5f * xv1 * (1.0f + erff(xv1 * 0.70710678f));
    ytA = y0;
    ytS = y1 - y0;
  }

  int bx = blockIdx.x, by = blockIdx.y;
  if (XSWZ) {
    // bijective chunked XCD swizzle: XCD k (= flat&7 round-robin) gets a
    // contiguous chunk of row-major block ids -> same-M-row blocks share L2.
    const int gx = gridDim.x;
    const int nwg = gx * gridDim.y;       // divisible by 8 here
    const int f = by * gx + bx;
    const int chunk = nwg >> 3;
    const int f2 = (f & 7) * chunk + (f >> 3);
    bx = f2 % gx;
    by = f2 / gx;
  }

  const int mBase = by * 256;
  const int nBase = bx * 256;
  const bf16_t* aTile = A + (size_t)mBase * K;
  const bf16_t* bTile = Bt + (size_t)nBase * K;

  f32x4 acc[8][4];
#pragma unroll
  for (int i = 0; i < 8; ++i)
#pragma unroll
    for (int j = 0; j < 4; ++j)
      acc[i][j] = (f32x4){0.f, 0.f, 0.f, 0.f};

  const int nT = K >> 6;  // even for both GEMMs (16, 64)
  const int rA0 = wr * 128 + l15;
  const int rB0 = wc * 64 + l15;

  // ---- prologue: stage all 4 units of K-tile 0 into buf0 (first-use order)
  stage_unit<6>(aTile, As0, K, 0, tid);    // U0: A i-half0
  stage_unit<5>(bTile, Bs0, K, 0, tid);    // U1: B j-half0
  stage_unit<5>(bTile, Bs0, K, 32, tid);   // U2: B j-half1
  stage_unit<6>(aTile, As0, K, 64, tid);   // U3: A i-half1
  asm volatile("s_waitcnt vmcnt(4)" ::: "memory");  // U0,U1 resident; U2,U3 in flight
  __builtin_amdgcn_s_barrier();

  for (int tt = 0; tt < nT; tt += 2) {
    // body0: read buf0, DMA-stage tile tt+1 into buf1 (nl always true: nT even)
    ktile(As0, Bs0, As1, Bs1,
          aTile + (size_t)(tt + 1) * 64, bTile + (size_t)(tt + 1) * 64,
          true, tid, rA0, rB0, lq, K, acc);
    // body1: read buf1, DMA-stage tile tt+2 into buf0
    ktile(As1, Bs1, As0, Bs0,
          aTile + (size_t)(tt + 2) * 64, bTile + (size_t)(tt + 2) * 64,
          (tt + 2 < nT), tid, rA0, rB0, lq, K, acc);
  }

  // ---- epilogue: bias + quantize (+ PWL GELU via register-table shuffle)
  float bj[4];
#pragma unroll
  for (int j = 0; j < 4; ++j)
    bj[j] = bias[nBase + wc * 64 + j * 16 + l15];

#pragma unroll
  for (int i = 0; i < 8; ++i) {
    const int rb = mBase + wr * 128 + i * 16 + lq * 4;
#pragma unroll
    for (int j = 0; j < 4; ++j) {
      const int cn = nBase + wc * 64 + j * 16 + l15;
#pragma unroll
      for (int r = 0; r < 4; ++r) {
        float c = acc[i][j][r] + bj[j];
        float v;
        if (GELU) {
          float xq = rintf(c * QS) * QINV;           // float2fix (Positional_0)
          float t = (xq + 4.0f) * 4.0f;              // exact: /0.25
          int ii = (int)t;
          ii = ii < 0 ? 0 : (ii > 31 ? 31 : ii);
          float f = t - (float)ii;
          float y0 = __shfl(ytA, ii);
          float sl = __shfl(ytS, ii);
          v = fmaf(f, sl, y0);
          v = (xq > 4.0f) ? xq : v;
          v = (xq < -4.0f) ? 0.0f : v;
          v = rintf(v * QS) * QINV;                  // quantize out (+Positional_1 idempotent)
        } else {
          v = rintf(c * QS) * QINV;                  // Positional_2
        }
        C[(size_t)(rb + r) * N + cn] = (OutT)v;
      }
    }
  }
}

__global__ void cvt_bf16_kernel(const float* __restrict__ in, bf16_t* __restrict__ out, int n4) {
  int idx = blockIdx.x * blockDim.x + threadIdx.x;
  if (idx < n4) {
    const float4 v = ((const float4*)in)[idx];
    bf16x4 o;
    o[0] = (bf16_t)v.x; o[1] = (bf16_t)v.y; o[2] = (bf16_t)v.z; o[3] = (bf16_t)v.w;
    ((bf16x4*)out)[idx] = o;
  }
}

// in: [R][C] f32 row-major -> out: [C][R] bf16 row-major
__global__ void transpose_cvt_kernel(const float* __restrict__ in, bf16_t* __restrict__ out,
                                     int R, int C) {
  __shared__ float t[32][33];
  const int c0 = blockIdx.x * 32;
  const int r0 = blockIdx.y * 32;
  const int tx = threadIdx.x;
  const int ty = threadIdx.y;  // 0..7
#pragma unroll
  for (int dy = 0; dy < 32; dy += 8)
    t[ty + dy][tx] = in[(size_t)(r0 + ty + dy) * C + c0 + tx];
  __syncthreads();
#pragma unroll
  for (int dy = 0; dy < 32; dy += 8)
    out[(size_t)(c0 + ty + dy) * R + r0 + tx] = (bf16_t)t[tx][ty + dy];
}

extern "C" void kernel_launch(void* const* d_in, const int* in_sizes, int n_in,
                              void* d_out, int out_size, void* d_ws, size_t ws_size,
                              hipStream_t stream) {
  const float* x  = (const float*)d_in[0];   // [32,512,1024] = [16384][1024]
  const float* w1 = (const float*)d_in[1];   // [1024][4096]
  const float* b1 = (const float*)d_in[2];   // [4096]
  const float* w2 = (const float*)d_in[3];   // [4096][1024]
  const float* b2 = (const float*)d_in[4];   // [1024]
  float* out = (float*)d_out;                // [16384][1024]

  const int M = 16384, D = 1024, F = 4096;

  char* ws = (char*)d_ws;
  size_t off = 0;
  bf16_t* xb  = (bf16_t*)(ws + off); off += (size_t)M * D * 2;  // 33.5 MB
  bf16_t* w1t = (bf16_t*)(ws + off); off += (size_t)D * F * 2;  //  8.4 MB
  bf16_t* w2t = (bf16_t*)(ws + off); off += (size_t)F * D * 2;  //  8.4 MB
  bf16_t* h   = (bf16_t*)(ws + off);                            // 134.2 MB

  cvt_bf16_kernel<<<(M * D / 4 + 255) / 256, 256, 0, stream>>>(x, xb, M * D / 4);
  transpose_cvt_kernel<<<dim3(F / 32, D / 32), dim3(32, 8), 0, stream>>>(w1, w1t, D, F);
  transpose_cvt_kernel<<<dim3(D / 32, F / 32), dim3(32, 8), 0, stream>>>(w2, w2t, F, D);

  // GEMM1 + quantize + PWL-GELU + quantize -> h (bf16)
  gemm_tile<true, bf16_t, false><<<dim3(F / 256, M / 256), 512, 0, stream>>>(xb, w1t, b1, h, M, F, D);
  // GEMM2 + quantize -> out (f32); h (134MB) re-read 4x -> XCD-chunked swizzle
  gemm_tile<false, float, true><<<dim3(D / 256, M / 256), 512, 0, stream>>>(h, w2t, b2, out, M, D, F);
}